// Round 4
// baseline (262.696 us; speedup 1.0000x reference)
//
#include <hip/hip_runtime.h>
#include <math.h>

#define NT 256
#define NB 2048

constexpr unsigned SVOX = 96u * 160u * 160u;   // 2,457,600 voxels per batch item
constexpr unsigned VTOT = 2u * SVOX;           // 4,915,200 voxels total
constexpr unsigned NQUAD = VTOT / 4u;          // 1,228,800 quads
constexpr unsigned CHUNK = NQUAD / NB;         // 600 quads per block (exact)
constexpr unsigned TAIL = CHUNK - 2u * NT;     // 88
constexpr double SMOOTH = 1e-5;
#define L2E 1.44269504088896340736f
#define LN2 0.69314718055994530942f

__device__ __forceinline__ float fexp2(float x) { return __builtin_amdgcn_exp2f(x); }
__device__ __forceinline__ float flog2(float x) { return __builtin_amdgcn_logf(x); }
__device__ __forceinline__ float frcp(float x)  { return __builtin_amdgcn_rcpf(x); }

struct Quad {
    float4 x0, x1, x2, x3;   // 4 softmax channels
    int4   tm;               // seg mask
    float4 ex;               // edge logits
    int4   em;               // edge mask
};

__device__ __forceinline__ Quad loadq(const float* __restrict__ seg,
                                      const float* __restrict__ edge,
                                      const int* __restrict__ sm,
                                      const int* __restrict__ em,
                                      unsigned v, unsigned segadd) {
    Quad q;
    const float* sb = seg + v + segadd;
    q.x0 = *(const float4*)(sb);
    q.x1 = *(const float4*)(sb + SVOX);
    q.x2 = *(const float4*)(sb + 2u * SVOX);
    q.x3 = *(const float4*)(sb + 3u * SVOX);
    q.tm = *(const int4*)(sm + v);
    q.ex = *(const float4*)(edge + v);
    q.em = *(const int4*)(em + v);
    return q;
}

// facc: 0..3 intersect[c], 4..7 sumprob[c], 8 bcePos, 9 bceNeg
// ccnt: packed 4x16-bit class counts; pncnt: pos<<16 | neg
__device__ __forceinline__ void procq(const Quad& q, float* facc,
                                      unsigned long long& ccnt, unsigned& pncnt) {
#define PROC(j) do {                                                           \
        const float e0 = fexp2(q.x0.j * L2E), e1 = fexp2(q.x1.j * L2E);        \
        const float e2 = fexp2(q.x2.j * L2E), e3 = fexp2(q.x3.j * L2E);        \
        const float inv = frcp(e0 + e1 + e2 + e3);                             \
        const float p0 = e0 * inv, p1 = e1 * inv, p2 = e2 * inv, p3 = e3 * inv;\
        facc[4] += p0; facc[5] += p1; facc[6] += p2; facc[7] += p3;            \
        const int t = q.tm.j;                                                  \
        facc[0] += (t == 0) ? p0 : 0.f;                                        \
        facc[1] += (t == 1) ? p1 : 0.f;                                        \
        facc[2] += (t == 2) ? p2 : 0.f;                                        \
        facc[3] += (t == 3) ? p3 : 0.f;                                        \
        ccnt += 1ull << (16 * t);                                              \
        const float xx = q.ex.j; const int tt = q.em.j;                        \
        const float sp = LN2 * flog2(1.f + fexp2(-fabsf(xx) * L2E));           \
        const float bce = fmaxf(xx, 0.f) - xx * (float)tt + sp;                \
        facc[8] += (tt == 1) ? bce : 0.f;                                      \
        facc[9] += (tt == 0) ? bce : 0.f;                                      \
        pncnt += (tt == 1) ? 0x10000u : 1u;                                    \
    } while (0)
    PROC(x); PROC(y); PROC(z); PROC(w);
#undef PROC
}

__global__ __launch_bounds__(NT)
void jedl_fused(const float* __restrict__ seg, const float* __restrict__ edge,
                const int* __restrict__ smask, const int* __restrict__ emask,
                float* __restrict__ part, unsigned* __restrict__ count,
                float* __restrict__ out) {
    const unsigned tid = threadIdx.x;
    const unsigned bid = blockIdx.x;
    const unsigned qbase = bid * CHUNK;
    // block-uniform batch select (chunks never straddle: 614,400 % 600 == 0)
    const unsigned segadd = (bid >= NB / 2) ? 3u * SVOX : 0u;

    float facc[10];
#pragma unroll
    for (int i = 0; i < 10; ++i) facc[i] = 0.f;
    unsigned long long ccnt = 0ull;
    unsigned pncnt = 0u;

    const bool tail = tid < TAIL;
    // 2-deep pipeline: load A, load B, proc A, load C(masked), proc B, proc C
    Quad qa = loadq(seg, edge, smask, emask, (qbase + tid) * 4u, segadd);
    Quad qb = loadq(seg, edge, smask, emask, (qbase + tid + NT) * 4u, segadd);
    procq(qa, facc, ccnt, pncnt);
    Quad qc;
    if (tail) qc = loadq(seg, edge, smask, emask, (qbase + tid + 2u * NT) * 4u, segadd);
    procq(qb, facc, ccnt, pncnt);
    if (tail) procq(qc, facc, ccnt, pncnt);

    // wave (64-lane) shuffle reduction
#pragma unroll
    for (int i = 0; i < 10; ++i) {
        float v = facc[i];
        for (int off = 32; off > 0; off >>= 1) v += __shfl_down(v, off);
        facc[i] = v;
    }
    for (int off = 32; off > 0; off >>= 1) ccnt += __shfl_down(ccnt, off);
    for (int off = 32; off > 0; off >>= 1) pncnt += __shfl_down(pncnt, off);

    __shared__ float wl[NT / 64][10];
    __shared__ unsigned long long wc[NT / 64];
    __shared__ unsigned wp[NT / 64];
    const int lane = (int)(tid & 63), wid = (int)(tid >> 6);
    if (lane == 0) {
#pragma unroll
        for (int i = 0; i < 10; ++i) wl[wid][i] = facc[i];
        wc[wid] = ccnt;
        wp[wid] = pncnt;
    }
    __syncthreads();
    if (tid == 0) {
        float s[10];
#pragma unroll
        for (int i = 0; i < 10; ++i)
            s[i] = wl[0][i] + wl[1][i] + wl[2][i] + wl[3][i];
        const unsigned long long c = wc[0] + wc[1] + wc[2] + wc[3];   // fields <= 768, no carry
        const unsigned pn = wp[0] + wp[1] + wp[2] + wp[3];
        // transposed layout for coalesced final reads: part[acc*NB + bid]
#pragma unroll
        for (int i = 0; i < 8; ++i) part[i * NB + bid] = s[i];
#pragma unroll
        for (int cix = 0; cix < 4; ++cix)
            part[(8 + cix) * NB + bid] = (float)((c >> (16 * cix)) & 0xffffull);
        part[12 * NB + bid] = s[8];                       // bce pos sum
        part[13 * NB + bid] = s[9];                       // bce neg sum
        part[14 * NB + bid] = (float)(pn >> 16);          // pos count
        part[15 * NB + bid] = (float)(pn & 0xffffu);      // neg count
    }

    // ---- last-block-done final reduction (device-scope, cross-XCD safe) ----
    __threadfence();                                  // release partials
    __shared__ unsigned ticket;
    if (tid == 0) ticket = atomicAdd(count, 1u);      // device-scope RMW
    __syncthreads();
    if (ticket != NB - 1) return;
    __threadfence();                                  // acquire: invalidate stale caches

    __shared__ double tot[16];
    const int w = wid;                                // 4 waves, 4 rows each
    for (int r = w; r < 16; r += NT / 64) {
        const float4* p4 = (const float4*)(part + r * NB);
        double d = 0.0;
#pragma unroll
        for (int it = 0; it < NB / 256; ++it) {       // 2048 floats = 8 x (64 lanes x float4)
            const float4 v = p4[it * 64 + lane];
            d += (double)v.x + (double)v.y + (double)v.z + (double)v.w;
        }
        for (int off = 32; off > 0; off >>= 1) d += __shfl_down(d, off);
        if (lane == 0) tot[r] = d;
    }
    __syncthreads();
    if (tid == 0) {
        double dsum = 0.0;
        for (int c = 0; c < 4; ++c)
            dsum += (2.0 * tot[c] + SMOOTH) / (tot[4 + c] + tot[8 + c] + SMOOTH);
        const double region = 1.0 - dsum / 4.0;
        const double bp = tot[12], bn = tot[13], pc = tot[14], nc = tot[15];
        const double sum = pc + nc;
        const double eloss = (nc * bp + pc * bn) / (sum * (double)VTOT);
        out[0] = (float)region;
        out[1] = (float)eloss;
    }
}

extern "C" void kernel_launch(void* const* d_in, const int* in_sizes, int n_in,
                              void* d_out, int out_size, void* d_ws, size_t ws_size,
                              hipStream_t stream) {
    const float* seg   = (const float*)d_in[0];
    const float* edge  = (const float*)d_in[1];
    const int*   smask = (const int*)d_in[2];
    const int*   emask = (const int*)d_in[3];
    float* out  = (float*)d_out;
    float* part = (float*)d_ws;                               // 16*NB floats = 128 KB
    unsigned* count = (unsigned*)((char*)d_ws + 16 * NB * sizeof(float));

    hipMemsetAsync(count, 0, sizeof(unsigned), stream);       // reset ticket each call
    jedl_fused<<<NB, NT, 0, stream>>>(seg, edge, smask, emask, part, count, out);
}

// Round 5
// 50.198 us; speedup vs baseline: 5.2331x; 5.2331x over previous
//
#include <hip/hip_runtime.h>
#include <math.h>

#define NT 256
#define NB 2048

constexpr unsigned SVOX = 96u * 160u * 160u;   // 2,457,600 voxels per batch item
constexpr unsigned VTOT = 2u * SVOX;           // 4,915,200 voxels total
constexpr unsigned NQUAD = VTOT / 4u;          // 1,228,800 quads
constexpr unsigned CHUNK = NQUAD / NB;         // 600 quads per block (exact)
constexpr unsigned TAIL = CHUNK - 2u * NT;     // 88
constexpr double SMOOTH = 1e-5;
#define L2E 1.44269504088896340736f
#define LN2 0.69314718055994530942f

__device__ __forceinline__ float fexp2(float x) { return __builtin_amdgcn_exp2f(x); }
__device__ __forceinline__ float flog2(float x) { return __builtin_amdgcn_logf(x); }
__device__ __forceinline__ float frcp(float x)  { return __builtin_amdgcn_rcpf(x); }

// Agent-scope (device) coherent scalar access: sc0/sc1 write-through stores and
// cache-bypassing loads -- visible cross-XCD WITHOUT any buffer_wbl2 L2 flush.
__device__ __forceinline__ void st_agent(float* p, float v) {
    __hip_atomic_store(p, v, __ATOMIC_RELAXED, __HIP_MEMORY_SCOPE_AGENT);
}
__device__ __forceinline__ float ld_agent(const float* p) {
    return __hip_atomic_load(p, __ATOMIC_RELAXED, __HIP_MEMORY_SCOPE_AGENT);
}

struct Quad {
    float4 x0, x1, x2, x3;   // 4 softmax channels
    int4   tm;               // seg mask
    float4 ex;               // edge logits
    int4   em;               // edge mask
};

__device__ __forceinline__ Quad loadq(const float* __restrict__ seg,
                                      const float* __restrict__ edge,
                                      const int* __restrict__ sm,
                                      const int* __restrict__ em,
                                      unsigned v, unsigned segadd) {
    Quad q;
    const float* sb = seg + v + segadd;
    q.x0 = *(const float4*)(sb);
    q.x1 = *(const float4*)(sb + SVOX);
    q.x2 = *(const float4*)(sb + 2u * SVOX);
    q.x3 = *(const float4*)(sb + 3u * SVOX);
    q.tm = *(const int4*)(sm + v);
    q.ex = *(const float4*)(edge + v);
    q.em = *(const int4*)(em + v);
    return q;
}

// facc: 0..3 intersect[c], 4..7 sumprob[c], 8 bcePos, 9 bceNeg
// ccnt: packed 4x16-bit class counts; pncnt: pos<<16 | neg
__device__ __forceinline__ void procq(const Quad& q, float* facc,
                                      unsigned long long& ccnt, unsigned& pncnt) {
#define PROC(j) do {                                                           \
        const float e0 = fexp2(q.x0.j * L2E), e1 = fexp2(q.x1.j * L2E);        \
        const float e2 = fexp2(q.x2.j * L2E), e3 = fexp2(q.x3.j * L2E);        \
        const float inv = frcp(e0 + e1 + e2 + e3);                             \
        const float p0 = e0 * inv, p1 = e1 * inv, p2 = e2 * inv, p3 = e3 * inv;\
        facc[4] += p0; facc[5] += p1; facc[6] += p2; facc[7] += p3;            \
        const int t = q.tm.j;                                                  \
        facc[0] += (t == 0) ? p0 : 0.f;                                        \
        facc[1] += (t == 1) ? p1 : 0.f;                                        \
        facc[2] += (t == 2) ? p2 : 0.f;                                        \
        facc[3] += (t == 3) ? p3 : 0.f;                                        \
        ccnt += 1ull << (16 * t);                                              \
        const float xx = q.ex.j; const int tt = q.em.j;                        \
        const float sp = LN2 * flog2(1.f + fexp2(-fabsf(xx) * L2E));           \
        const float bce = fmaxf(xx, 0.f) - xx * (float)tt + sp;                \
        facc[8] += (tt == 1) ? bce : 0.f;                                      \
        facc[9] += (tt == 0) ? bce : 0.f;                                      \
        pncnt += (tt == 1) ? 0x10000u : 1u;                                    \
    } while (0)
    PROC(x); PROC(y); PROC(z); PROC(w);
#undef PROC
}

__global__ __launch_bounds__(NT)
void jedl_fused(const float* __restrict__ seg, const float* __restrict__ edge,
                const int* __restrict__ smask, const int* __restrict__ emask,
                float* __restrict__ part, unsigned* __restrict__ count,
                float* __restrict__ out) {
    const unsigned tid = threadIdx.x;
    const unsigned bid = blockIdx.x;
    const unsigned qbase = bid * CHUNK;
    // block-uniform batch select (chunks never straddle: 614,400 % 600 == 0)
    const unsigned segadd = (bid >= NB / 2) ? 3u * SVOX : 0u;

    float facc[10];
#pragma unroll
    for (int i = 0; i < 10; ++i) facc[i] = 0.f;
    unsigned long long ccnt = 0ull;
    unsigned pncnt = 0u;

    const bool tail = tid < TAIL;
    // 2-deep pipeline: load A, load B, proc A, load C(masked), proc B, proc C
    Quad qa = loadq(seg, edge, smask, emask, (qbase + tid) * 4u, segadd);
    Quad qb = loadq(seg, edge, smask, emask, (qbase + tid + NT) * 4u, segadd);
    procq(qa, facc, ccnt, pncnt);
    Quad qc;
    if (tail) qc = loadq(seg, edge, smask, emask, (qbase + tid + 2u * NT) * 4u, segadd);
    procq(qb, facc, ccnt, pncnt);
    if (tail) procq(qc, facc, ccnt, pncnt);

    // wave (64-lane) shuffle reduction
#pragma unroll
    for (int i = 0; i < 10; ++i) {
        float v = facc[i];
        for (int off = 32; off > 0; off >>= 1) v += __shfl_down(v, off);
        facc[i] = v;
    }
    for (int off = 32; off > 0; off >>= 1) ccnt += __shfl_down(ccnt, off);
    for (int off = 32; off > 0; off >>= 1) pncnt += __shfl_down(pncnt, off);

    __shared__ float wl[NT / 64][10];
    __shared__ unsigned long long wc[NT / 64];
    __shared__ unsigned wp[NT / 64];
    const int lane = (int)(tid & 63), wid = (int)(tid >> 6);
    if (lane == 0) {
#pragma unroll
        for (int i = 0; i < 10; ++i) wl[wid][i] = facc[i];
        wc[wid] = ccnt;
        wp[wid] = pncnt;
    }
    __syncthreads();

    __shared__ unsigned ticket;
    if (tid == 0) {
        float s[10];
#pragma unroll
        for (int i = 0; i < 10; ++i)
            s[i] = wl[0][i] + wl[1][i] + wl[2][i] + wl[3][i];
        const unsigned long long c = wc[0] + wc[1] + wc[2] + wc[3];   // fields <= 768, no carry
        const unsigned pn = wp[0] + wp[1] + wp[2] + wp[3];
        // publish partials write-through (coherence point), transposed layout
#pragma unroll
        for (int i = 0; i < 8; ++i) st_agent(&part[i * NB + bid], s[i]);
#pragma unroll
        for (int cix = 0; cix < 4; ++cix)
            st_agent(&part[(8 + cix) * NB + bid], (float)((c >> (16 * cix)) & 0xffffull));
        st_agent(&part[12 * NB + bid], s[8]);                  // bce pos sum
        st_agent(&part[13 * NB + bid], s[9]);                  // bce neg sum
        st_agent(&part[14 * NB + bid], (float)(pn >> 16));     // pos count
        st_agent(&part[15 * NB + bid], (float)(pn & 0xffffu)); // neg count
        // ensure stores reached the coherence point, then take a ticket.
        asm volatile("s_waitcnt vmcnt(0)" ::: "memory");
        ticket = __hip_atomic_fetch_add(count, 1u, __ATOMIC_RELAXED,
                                        __HIP_MEMORY_SCOPE_AGENT);
    }
    __syncthreads();
    if (ticket != NB - 1) return;

    // ---- elected last block: final reduction via coherent (sc1) loads ----
    __shared__ double tot[16];
    for (int r = wid; r < 16; r += NT / 64) {        // 4 waves, 4 rows each
        const float* row = part + r * NB;
        double d = 0.0;
#pragma unroll
        for (int it = 0; it < NB / 64; ++it)         // 32 coalesced scalar loads/lane
            d += (double)ld_agent(&row[it * 64 + lane]);
        for (int off = 32; off > 0; off >>= 1) d += __shfl_down(d, off);
        if (lane == 0) tot[r] = d;
    }
    __syncthreads();
    if (tid == 0) {
        double dsum = 0.0;
        for (int c = 0; c < 4; ++c)
            dsum += (2.0 * tot[c] + SMOOTH) / (tot[4 + c] + tot[8 + c] + SMOOTH);
        const double region = 1.0 - dsum / 4.0;
        const double bp = tot[12], bn = tot[13], pc = tot[14], nc = tot[15];
        const double sum = pc + nc;
        const double eloss = (nc * bp + pc * bn) / (sum * (double)VTOT);
        out[0] = (float)region;
        out[1] = (float)eloss;
    }
}

extern "C" void kernel_launch(void* const* d_in, const int* in_sizes, int n_in,
                              void* d_out, int out_size, void* d_ws, size_t ws_size,
                              hipStream_t stream) {
    const float* seg   = (const float*)d_in[0];
    const float* edge  = (const float*)d_in[1];
    const int*   smask = (const int*)d_in[2];
    const int*   emask = (const int*)d_in[3];
    float* out  = (float*)d_out;
    float* part = (float*)d_ws;                               // 16*NB floats = 128 KB
    unsigned* count = (unsigned*)((char*)d_ws + 16 * NB * sizeof(float));

    hipMemsetAsync(count, 0, sizeof(unsigned), stream);       // reset ticket each call
    jedl_fused<<<NB, NT, 0, stream>>>(seg, edge, smask, emask, part, count, out);
}

// Round 6
// 31.968 us; speedup vs baseline: 8.2174x; 1.5703x over previous
//
#include <hip/hip_runtime.h>
#include <math.h>

#define NT 256
#define NB 2048

constexpr unsigned SVOX = 96u * 160u * 160u;   // 2,457,600 voxels per batch item
constexpr unsigned VTOT = 2u * SVOX;           // 4,915,200 voxels total
constexpr unsigned NQUAD = VTOT / 4u;          // 1,228,800 quads
constexpr unsigned CHUNK = NQUAD / NB;         // 600 quads per block (exact)
constexpr unsigned TAIL = CHUNK - 2u * NT;     // 88
constexpr double SMOOTH = 1e-5;
#define L2E 1.44269504088896340736f
#define LN2 0.69314718055994530942f

__device__ __forceinline__ float fexp2(float x) { return __builtin_amdgcn_exp2f(x); }
__device__ __forceinline__ float flog2(float x) { return __builtin_amdgcn_logf(x); }
__device__ __forceinline__ float frcp(float x)  { return __builtin_amdgcn_rcpf(x); }

struct Quad {
    float4 x0, x1, x2, x3;   // 4 softmax channels
    int4   tm;               // seg mask
    float4 ex;               // edge logits
    int4   em;               // edge mask
};

__device__ __forceinline__ Quad loadq(const float* __restrict__ seg,
                                      const float* __restrict__ edge,
                                      const int* __restrict__ sm,
                                      const int* __restrict__ em,
                                      unsigned v, unsigned segadd) {
    Quad q;
    const float* sb = seg + v + segadd;
    q.x0 = *(const float4*)(sb);
    q.x1 = *(const float4*)(sb + SVOX);
    q.x2 = *(const float4*)(sb + 2u * SVOX);
    q.x3 = *(const float4*)(sb + 3u * SVOX);
    q.tm = *(const int4*)(sm + v);
    q.ex = *(const float4*)(edge + v);
    q.em = *(const int4*)(em + v);
    return q;
}

// facc: 0..3 intersect[c], 4..7 sumprob[c], 8 bcePos, 9 bceNeg
// ccnt: packed 4x16-bit class counts; pncnt: pos<<16 | neg
__device__ __forceinline__ void procq(const Quad& q, float* facc,
                                      unsigned long long& ccnt, unsigned& pncnt) {
#define PROC(j) do {                                                           \
        const float e0 = fexp2(q.x0.j * L2E), e1 = fexp2(q.x1.j * L2E);        \
        const float e2 = fexp2(q.x2.j * L2E), e3 = fexp2(q.x3.j * L2E);        \
        const float inv = frcp(e0 + e1 + e2 + e3);                             \
        const float p0 = e0 * inv, p1 = e1 * inv, p2 = e2 * inv, p3 = e3 * inv;\
        facc[4] += p0; facc[5] += p1; facc[6] += p2; facc[7] += p3;            \
        const int t = q.tm.j;                                                  \
        facc[0] += (t == 0) ? p0 : 0.f;                                        \
        facc[1] += (t == 1) ? p1 : 0.f;                                        \
        facc[2] += (t == 2) ? p2 : 0.f;                                        \
        facc[3] += (t == 3) ? p3 : 0.f;                                        \
        ccnt += 1ull << (16 * t);                                              \
        const float xx = q.ex.j; const int tt = q.em.j;                        \
        const float sp = LN2 * flog2(1.f + fexp2(-fabsf(xx) * L2E));           \
        const float bce = fmaxf(xx, 0.f) - xx * (float)tt + sp;                \
        facc[8] += (tt == 1) ? bce : 0.f;                                      \
        facc[9] += (tt == 0) ? bce : 0.f;                                      \
        pncnt += (tt == 1) ? 0x10000u : 1u;                                    \
    } while (0)
    PROC(x); PROC(y); PROC(z); PROC(w);
#undef PROC
}

__global__ __launch_bounds__(NT)
void jedl_stage1(const float* __restrict__ seg, const float* __restrict__ edge,
                 const int* __restrict__ smask, const int* __restrict__ emask,
                 float* __restrict__ part) {
    const unsigned tid = threadIdx.x;
    const unsigned bid = blockIdx.x;
    const unsigned qbase = bid * CHUNK;
    // block-uniform batch select (chunks never straddle: 614,400 % 600 == 0)
    const unsigned segadd = (bid >= NB / 2) ? 3u * SVOX : 0u;

    float facc[10];
#pragma unroll
    for (int i = 0; i < 10; ++i) facc[i] = 0.f;
    unsigned long long ccnt = 0ull;
    unsigned pncnt = 0u;

    const bool tail = tid < TAIL;
    // 2-deep pipeline: load A, load B, proc A, load C(masked), proc B, proc C
    Quad qa = loadq(seg, edge, smask, emask, (qbase + tid) * 4u, segadd);
    Quad qb = loadq(seg, edge, smask, emask, (qbase + tid + NT) * 4u, segadd);
    procq(qa, facc, ccnt, pncnt);
    Quad qc;
    if (tail) qc = loadq(seg, edge, smask, emask, (qbase + tid + 2u * NT) * 4u, segadd);
    procq(qb, facc, ccnt, pncnt);
    if (tail) procq(qc, facc, ccnt, pncnt);

    // wave (64-lane) shuffle reduction
#pragma unroll
    for (int i = 0; i < 10; ++i) {
        float v = facc[i];
        for (int off = 32; off > 0; off >>= 1) v += __shfl_down(v, off);
        facc[i] = v;
    }
    for (int off = 32; off > 0; off >>= 1) ccnt += __shfl_down(ccnt, off);
    for (int off = 32; off > 0; off >>= 1) pncnt += __shfl_down(pncnt, off);

    __shared__ float wl[NT / 64][10];
    __shared__ unsigned long long wc[NT / 64];
    __shared__ unsigned wp[NT / 64];
    const int lane = (int)(tid & 63), wid = (int)(tid >> 6);
    if (lane == 0) {
#pragma unroll
        for (int i = 0; i < 10; ++i) wl[wid][i] = facc[i];
        wc[wid] = ccnt;
        wp[wid] = pncnt;
    }
    __syncthreads();
    if (tid == 0) {
        float s[10];
#pragma unroll
        for (int i = 0; i < 10; ++i)
            s[i] = wl[0][i] + wl[1][i] + wl[2][i] + wl[3][i];
        const unsigned long long c = wc[0] + wc[1] + wc[2] + wc[3];   // fields <= 768, no carry
        const unsigned pn = wp[0] + wp[1] + wp[2] + wp[3];
        // transposed layout for coalesced stage-2 reads: part[acc*NB + bid]
#pragma unroll
        for (int i = 0; i < 8; ++i) part[i * NB + bid] = s[i];
#pragma unroll
        for (int cix = 0; cix < 4; ++cix)
            part[(8 + cix) * NB + bid] = (float)((c >> (16 * cix)) & 0xffffull);
        part[12 * NB + bid] = s[8];                       // bce pos sum
        part[13 * NB + bid] = s[9];                       // bce neg sum
        part[14 * NB + bid] = (float)(pn >> 16);          // pos count
        part[15 * NB + bid] = (float)(pn & 0xffffu);      // neg count
    }
}

__global__ __launch_bounds__(NT)
void jedl_stage2(const float* __restrict__ part, float* __restrict__ out) {
    __shared__ double tot[16];
    const int tid = threadIdx.x;
    const int w = tid >> 6, lane = tid & 63;         // 4 waves, 4 rows each
    for (int r = w; r < 16; r += NT / 64) {
        const float4* p4 = (const float4*)(part + r * NB);
        double d = 0.0;
#pragma unroll
        for (int it = 0; it < NB / 256; ++it) {      // 8 x (64 lanes x float4) = 2048 floats
            const float4 v = p4[it * 64 + lane];
            d += (double)v.x + (double)v.y + (double)v.z + (double)v.w;
        }
        for (int off = 32; off > 0; off >>= 1) d += __shfl_down(d, off);
        if (lane == 0) tot[r] = d;
    }
    __syncthreads();
    if (tid == 0) {
        double dsum = 0.0;
        for (int c = 0; c < 4; ++c)
            dsum += (2.0 * tot[c] + SMOOTH) / (tot[4 + c] + tot[8 + c] + SMOOTH);
        const double region = 1.0 - dsum / 4.0;
        const double bp = tot[12], bn = tot[13], pc = tot[14], nc = tot[15];
        const double sum = pc + nc;
        const double eloss = (nc * bp + pc * bn) / (sum * (double)VTOT);
        out[0] = (float)region;
        out[1] = (float)eloss;
    }
}

extern "C" void kernel_launch(void* const* d_in, const int* in_sizes, int n_in,
                              void* d_out, int out_size, void* d_ws, size_t ws_size,
                              hipStream_t stream) {
    const float* seg   = (const float*)d_in[0];
    const float* edge  = (const float*)d_in[1];
    const int*   smask = (const int*)d_in[2];
    const int*   emask = (const int*)d_in[3];
    float* out  = (float*)d_out;
    float* part = (float*)d_ws;   // 16 * NB floats = 128 KB

    jedl_stage1<<<NB, NT, 0, stream>>>(seg, edge, smask, emask, part);
    jedl_stage2<<<1, NT, 0, stream>>>(part, out);
}

// Round 7
// 31.232 us; speedup vs baseline: 8.4110x; 1.0236x over previous
//
#include <hip/hip_runtime.h>
#include <math.h>

#define NT 256
#define NT2 1024
#define NB 2048

constexpr unsigned SVOX = 96u * 160u * 160u;   // 2,457,600 voxels per batch item
constexpr unsigned VTOT = 2u * SVOX;           // 4,915,200 voxels total
constexpr unsigned NQUAD = VTOT / 4u;          // 1,228,800 quads
constexpr unsigned CHUNK = NQUAD / NB;         // 600 quads per block (exact)
constexpr unsigned TAIL = CHUNK - 2u * NT;     // 88 = 4 waves x 22 lanes
constexpr unsigned TAILW = TAIL / 4u;          // 22 tail lanes per wave
constexpr double SMOOTH = 1e-5;
#define L2E 1.44269504088896340736f
#define LN2 0.69314718055994530942f

__device__ __forceinline__ float fexp2(float x) { return __builtin_amdgcn_exp2f(x); }
__device__ __forceinline__ float flog2(float x) { return __builtin_amdgcn_logf(x); }
__device__ __forceinline__ float frcp(float x)  { return __builtin_amdgcn_rcpf(x); }

struct Quad {
    float4 x0, x1, x2, x3;   // 4 softmax channels
    int4   tm;               // seg mask
    float4 ex;               // edge logits
    int4   em;               // edge mask
};

__device__ __forceinline__ Quad loadq(const float* __restrict__ seg,
                                      const float* __restrict__ edge,
                                      const int* __restrict__ sm,
                                      const int* __restrict__ em,
                                      unsigned v, unsigned segadd) {
    Quad q;
    const float* sb = seg + v + segadd;
    q.x0 = *(const float4*)(sb);
    q.x1 = *(const float4*)(sb + SVOX);
    q.x2 = *(const float4*)(sb + 2u * SVOX);
    q.x3 = *(const float4*)(sb + 3u * SVOX);
    q.tm = *(const int4*)(sm + v);
    q.ex = *(const float4*)(edge + v);
    q.em = *(const int4*)(em + v);
    return q;
}

// facc: 0..3 intersect[c], 4..7 sumprob[c], 8 bcePos, 9 bceNeg
// ccnt: packed 4x16-bit class counts; pncnt: pos<<16 | neg
__device__ __forceinline__ void procq(const Quad& q, float* facc,
                                      unsigned long long& ccnt, unsigned& pncnt) {
#define PROC(j) do {                                                           \
        const float e0 = fexp2(q.x0.j * L2E), e1 = fexp2(q.x1.j * L2E);        \
        const float e2 = fexp2(q.x2.j * L2E), e3 = fexp2(q.x3.j * L2E);        \
        const float inv = frcp(e0 + e1 + e2 + e3);                             \
        const float p0 = e0 * inv, p1 = e1 * inv, p2 = e2 * inv, p3 = e3 * inv;\
        facc[4] += p0; facc[5] += p1; facc[6] += p2; facc[7] += p3;            \
        const int t = q.tm.j;                                                  \
        facc[0] += (t == 0) ? p0 : 0.f;                                        \
        facc[1] += (t == 1) ? p1 : 0.f;                                        \
        facc[2] += (t == 2) ? p2 : 0.f;                                        \
        facc[3] += (t == 3) ? p3 : 0.f;                                        \
        ccnt += 1ull << (16 * t);                                              \
        const float xx = q.ex.j; const int tt = q.em.j;                        \
        const float sp = LN2 * flog2(1.f + fexp2(-fabsf(xx) * L2E));           \
        const float bce = fmaxf(xx, 0.f) - xx * (float)tt + sp;                \
        facc[8] += (tt == 1) ? bce : 0.f;                                      \
        facc[9] += (tt == 0) ? bce : 0.f;                                      \
        pncnt += (tt == 1) ? 0x10000u : 1u;                                    \
    } while (0)
    PROC(x); PROC(y); PROC(z); PROC(w);
#undef PROC
}

__global__ __launch_bounds__(NT)
void jedl_stage1(const float* __restrict__ seg, const float* __restrict__ edge,
                 const int* __restrict__ smask, const int* __restrict__ emask,
                 float* __restrict__ part) {
    const unsigned tid = threadIdx.x;
    const unsigned bid = blockIdx.x;
    const unsigned qbase = bid * CHUNK;
    // block-uniform batch select (chunks never straddle: 614,400 % 600 == 0)
    const unsigned segadd = (bid >= NB / 2) ? 3u * SVOX : 0u;

    const int lane = (int)(tid & 63), wid = (int)(tid >> 6);

    float facc[10];
#pragma unroll
    for (int i = 0; i < 10; ++i) facc[i] = 0.f;
    unsigned long long ccnt = 0ull;
    unsigned pncnt = 0u;

    // Tail spread across all 4 waves (22 lanes each) so all 4 SIMDs stay
    // balanced during the 3rd pass (vs tid<88 = SIMDs 0-1 only).
    const bool tail = lane < (int)TAILW;
    const unsigned tailq = qbase + 2u * NT + (unsigned)(wid * (int)TAILW + lane);

    // 2-deep pipeline: load A, load B, proc A, load C(masked), proc B, proc C
    Quad qa = loadq(seg, edge, smask, emask, (qbase + tid) * 4u, segadd);
    Quad qb = loadq(seg, edge, smask, emask, (qbase + tid + NT) * 4u, segadd);
    procq(qa, facc, ccnt, pncnt);
    Quad qc;
    if (tail) qc = loadq(seg, edge, smask, emask, tailq * 4u, segadd);
    procq(qb, facc, ccnt, pncnt);
    if (tail) procq(qc, facc, ccnt, pncnt);

    // wave (64-lane) shuffle reduction
#pragma unroll
    for (int i = 0; i < 10; ++i) {
        float v = facc[i];
        for (int off = 32; off > 0; off >>= 1) v += __shfl_down(v, off);
        facc[i] = v;
    }
    for (int off = 32; off > 0; off >>= 1) ccnt += __shfl_down(ccnt, off);
    for (int off = 32; off > 0; off >>= 1) pncnt += __shfl_down(pncnt, off);

    __shared__ float wl[NT / 64][10];
    __shared__ unsigned long long wc[NT / 64];
    __shared__ unsigned wp[NT / 64];
    if (lane == 0) {
#pragma unroll
        for (int i = 0; i < 10; ++i) wl[wid][i] = facc[i];
        wc[wid] = ccnt;
        wp[wid] = pncnt;
    }
    __syncthreads();
    if (tid == 0) {
        float s[10];
#pragma unroll
        for (int i = 0; i < 10; ++i)
            s[i] = wl[0][i] + wl[1][i] + wl[2][i] + wl[3][i];
        const unsigned long long c = wc[0] + wc[1] + wc[2] + wc[3];   // fields <= 768, no carry
        const unsigned pn = wp[0] + wp[1] + wp[2] + wp[3];
        // transposed layout for coalesced stage-2 reads: part[acc*NB + bid]
#pragma unroll
        for (int i = 0; i < 8; ++i) part[i * NB + bid] = s[i];
#pragma unroll
        for (int cix = 0; cix < 4; ++cix)
            part[(8 + cix) * NB + bid] = (float)((c >> (16 * cix)) & 0xffffull);
        part[12 * NB + bid] = s[8];                       // bce pos sum
        part[13 * NB + bid] = s[9];                       // bce neg sum
        part[14 * NB + bid] = (float)(pn >> 16);          // pos count
        part[15 * NB + bid] = (float)(pn & 0xffffu);      // neg count
    }
}

__global__ __launch_bounds__(NT2)
void jedl_stage2(const float* __restrict__ part, float* __restrict__ out) {
    __shared__ double tot[16];
    const int tid = threadIdx.x;
    const int w = tid >> 6, lane = tid & 63;      // 16 waves, one accumulator row each
    const float4* p4 = (const float4*)(part + w * NB);
    double d = 0.0;
#pragma unroll
    for (int it = 0; it < NB / (64 * 4); ++it) {
        const float4 v = p4[it * 64 + lane];
        d += (double)v.x + (double)v.y + (double)v.z + (double)v.w;
    }
    for (int off = 32; off > 0; off >>= 1) d += __shfl_down(d, off);
    if (lane == 0) tot[w] = d;
    __syncthreads();
    if (tid == 0) {
        double dsum = 0.0;
        for (int c = 0; c < 4; ++c)
            dsum += (2.0 * tot[c] + SMOOTH) / (tot[4 + c] + tot[8 + c] + SMOOTH);
        const double region = 1.0 - dsum / 4.0;
        const double bp = tot[12], bn = tot[13], pc = tot[14], nc = tot[15];
        const double sum = pc + nc;
        const double eloss = (nc * bp + pc * bn) / (sum * (double)VTOT);
        out[0] = (float)region;
        out[1] = (float)eloss;
    }
}

extern "C" void kernel_launch(void* const* d_in, const int* in_sizes, int n_in,
                              void* d_out, int out_size, void* d_ws, size_t ws_size,
                              hipStream_t stream) {
    const float* seg   = (const float*)d_in[0];
    const float* edge  = (const float*)d_in[1];
    const int*   smask = (const int*)d_in[2];
    const int*   emask = (const int*)d_in[3];
    float* out  = (float*)d_out;
    float* part = (float*)d_ws;   // 16 * NB floats = 128 KB

    jedl_stage1<<<NB, NT, 0, stream>>>(seg, edge, smask, emask, part);
    jedl_stage2<<<1, NT2, 0, stream>>>(part, out);
}